// Round 1
// baseline (172.785 us; speedup 1.0000x reference)
//
#include <hip/hip_runtime.h>

#define Wd 512
#define Hd 512
#define NIMG 48                 // 16 batch * 3 channels
#define W4 (Wd/4)               // 128 float4-groups per row
constexpr float INV_N = 1.0f / (float)((long long)NIMG * Hd * Wd);

// Scharr on a 3x6 window; pixel j uses columns j..j+2 of rows r0,r1,r2.
__device__ __forceinline__ float scharr_pix(const float r0[6], const float r1[6],
                                            const float r2[6], int j) {
    float tl = r0[j], tm = r0[j + 1], tr = r0[j + 2];
    float ml = r1[j],                  mr = r1[j + 2];
    float bl = r2[j], bm = r2[j + 1], br = r2[j + 2];
    float gx = 3.f * (tr - tl) + 10.f * (mr - ml) + 3.f * (br - bl);
    float gy = 3.f * (bl - tl) + 10.f * (bm - tm) + 3.f * (br - tr);
    return fabsf(gx) + fabsf(gy);
}

// Load columns [w4-1 .. w4+4] of one row into r[6]: one float4 + two scalars.
__device__ __forceinline__ void load_row6(const float* __restrict__ row, int w4, float r[6]) {
    float4 b = *reinterpret_cast<const float4*>(row + w4);
    r[0] = row[w4 - 1];
    r[1] = b.x; r[2] = b.y; r[3] = b.z; r[4] = b.w;
    r[5] = row[w4 + 4];
}

// Zero-padded scalar fetch (border path only).
__device__ __forceinline__ float atZ(const float* __restrict__ img, int h, int w) {
    if ((unsigned)h >= (unsigned)Hd || (unsigned)w >= (unsigned)Wd) return 0.f;
    return img[h * Wd + w];
}

__device__ __forceinline__ float scharr_slow(const float* __restrict__ img, int h, int w) {
    float tl = atZ(img, h - 1, w - 1), tm = atZ(img, h - 1, w), tr = atZ(img, h - 1, w + 1);
    float ml = atZ(img, h,     w - 1),                           mr = atZ(img, h,     w + 1);
    float bl = atZ(img, h + 1, w - 1), bm = atZ(img, h + 1, w), br = atZ(img, h + 1, w + 1);
    float gx = 3.f * (tr - tl) + 10.f * (mr - ml) + 3.f * (br - bl);
    float gy = 3.f * (bl - tl) + 10.f * (bm - tm) + 3.f * (br - tr);
    return fabsf(gx) + fabsf(gy);
}

__global__ void __launch_bounds__(256)
scharr_loss_kernel(const float* __restrict__ x, const float* __restrict__ gt,
                   float* __restrict__ out) {
    int g = blockIdx.x * 256 + threadIdx.x;   // one float4-group of 4 pixels
    int wq  = g & (W4 - 1);                   // group index within row: 0..127
    int h   = (g >> 7) & (Hd - 1);            // row
    int img = g >> 16;                        // image (b*c), 128*512 = 65536
    int w4  = wq * 4;

    const float* __restrict__ xb = x  + (size_t)img * Hd * Wd;
    const float* __restrict__ gb = gt + (size_t)img * Hd * Wd;

    float sum = 0.f;
    if (h >= 1 && h <= Hd - 2 && w4 >= 4 && w4 <= Wd - 8) {
        // interior fast path: 3 rows x (float4 + 2 scalars) per image
        float rx0[6], rx1[6], rx2[6], rg0[6], rg1[6], rg2[6];
        const float* xr = xb + (size_t)(h - 1) * Wd;
        const float* gr = gb + (size_t)(h - 1) * Wd;
        load_row6(xr,           w4, rx0);
        load_row6(xr + Wd,      w4, rx1);
        load_row6(xr + 2 * Wd,  w4, rx2);
        load_row6(gr,           w4, rg0);
        load_row6(gr + Wd,      w4, rg1);
        load_row6(gr + 2 * Wd,  w4, rg2);
        #pragma unroll
        for (int j = 0; j < 4; ++j) {
            float a = scharr_pix(rx0, rx1, rx2, j);
            float b = scharr_pix(rg0, rg1, rg2, j);
            sum += fabsf(a - b);
        }
    } else {
        // border path (h==0, h==511, or w-group touching a vertical edge)
        #pragma unroll
        for (int j = 0; j < 4; ++j) {
            int w = w4 + j;
            float a = scharr_slow(xb, h, w);
            float b = scharr_slow(gb, h, w);
            sum += fabsf(a - b);
        }
    }

    // wave(64) reduce, then cross-wave via LDS, one atomic per block
    #pragma unroll
    for (int off = 32; off > 0; off >>= 1)
        sum += __shfl_down(sum, off, 64);

    __shared__ float ws[4];
    int lane = threadIdx.x & 63;
    int wid  = threadIdx.x >> 6;
    if (lane == 0) ws[wid] = sum;
    __syncthreads();
    if (threadIdx.x == 0) {
        float s = ws[0] + ws[1] + ws[2] + ws[3];
        atomicAdd(out, s * INV_N);
    }
}

extern "C" void kernel_launch(void* const* d_in, const int* in_sizes, int n_in,
                              void* d_out, int out_size, void* d_ws, size_t ws_size,
                              hipStream_t stream) {
    const float* x  = (const float*)d_in[0];
    const float* gt = (const float*)d_in[1];
    float* out = (float*)d_out;

    // d_out is poisoned once before timing and never re-poisoned; zero it every call.
    hipMemsetAsync(out, 0, sizeof(float), stream);

    const int total_groups = NIMG * Hd * W4;          // 48 * 512 * 128 = 3,145,728
    const int blocks = total_groups / 256;            // 12,288
    scharr_loss_kernel<<<blocks, 256, 0, stream>>>(x, gt, out);
}

// Round 2
// 31.398 us; speedup vs baseline: 5.5031x; 5.5031x over previous
//
#include <hip/hip_runtime.h>

#define Wd 512
#define Hd 512
#define NIMG 48                 // 16 batch * 3 channels
#define ROWS 8                  // output rows per thread
#define NBLOCKS 1536            // 48 img * (512/8) rowblocks * 128 wq / 256 thr
constexpr float INV_N = 1.0f / (float)((long long)NIMG * Hd * Wd);

// Scharr on a 3x6 window; pixel j uses columns j..j+2 of rows r0,r1,r2.
__device__ __forceinline__ float scharr_pix(const float r0[6], const float r1[6],
                                            const float r2[6], int j) {
    float tl = r0[j], tm = r0[j + 1], tr = r0[j + 2];
    float ml = r1[j],                  mr = r1[j + 2];
    float bl = r2[j], bm = r2[j + 1], br = r2[j + 2];
    float gx = 3.f * (tr - tl) + 10.f * (mr - ml) + 3.f * (br - bl);
    float gy = 3.f * (bl - tl) + 10.f * (bm - tm) + 3.f * (br - tr);
    return fabsf(gx) + fabsf(gy);
}

// Load columns [w4-1 .. w4+4] of row h (zero if row OOB; edge cols zero-masked).
// h is wave-uniform -> the h-branch does not diverge.
__device__ __forceinline__ void load_row(const float* __restrict__ img, int h,
                                         int w4, float r[6]) {
    if ((unsigned)h < (unsigned)Hd) {
        const float* row = img + (size_t)h * Wd;
        float4 b = *reinterpret_cast<const float4*>(row + w4);
        r[1] = b.x; r[2] = b.y; r[3] = b.z; r[4] = b.w;
        int wl = (w4 > 0) ? (w4 - 1) : 0;            // clamped addr, always valid
        int wr = (w4 + 4 < Wd) ? (w4 + 4) : (Wd - 1);
        float lv = row[wl];
        float rv = row[wr];
        r[0] = (w4 > 0) ? lv : 0.f;                  // cndmask, no divergence
        r[5] = (w4 + 4 < Wd) ? rv : 0.f;
    } else {
        r[0] = r[1] = r[2] = r[3] = r[4] = r[5] = 0.f;
    }
}

__global__ void __launch_bounds__(256)
scharr_loss_kernel(const float* __restrict__ x, const float* __restrict__ gt,
                   float* __restrict__ partials) {
    // tid -> wq (0..127) within row, sub (0..1) -> rowblock
    int wq  = threadIdx.x & 127;
    int sub = threadIdx.x >> 7;
    int rb  = blockIdx.x * 2 + sub;       // 0 .. 48*64-1
    int img = rb >> 6;
    int h0  = (rb & 63) * ROWS;
    int w4  = wq * 4;

    const float* __restrict__ xb = x  + (size_t)img * Hd * Wd;
    const float* __restrict__ gb = gt + (size_t)img * Hd * Wd;

    // Rolling 3-row windows, fully unrolled -> all indices compile-time.
    float ax[3][6], ag[3][6];
    load_row(xb, h0 - 1, w4, ax[0]);
    load_row(xb, h0,     w4, ax[1]);
    load_row(gb, h0 - 1, w4, ag[0]);
    load_row(gb, h0,     w4, ag[1]);

    float sum = 0.f;
    #pragma unroll
    for (int i = 0; i < ROWS; ++i) {
        const int c0 = i % 3, c1 = (i + 1) % 3, c2 = (i + 2) % 3;
        load_row(xb, h0 + i + 1, w4, ax[c2]);
        load_row(gb, h0 + i + 1, w4, ag[c2]);
        #pragma unroll
        for (int j = 0; j < 4; ++j) {
            float a = scharr_pix(ax[c0], ax[c1], ax[c2], j);
            float b = scharr_pix(ag[c0], ag[c1], ag[c2], j);
            sum += fabsf(a - b);
        }
    }

    // wave(64) reduce, then cross-wave via LDS, one plain store per block
    #pragma unroll
    for (int off = 32; off > 0; off >>= 1)
        sum += __shfl_down(sum, off, 64);

    __shared__ float ws[4];
    int lane = threadIdx.x & 63;
    int wid  = threadIdx.x >> 6;
    if (lane == 0) ws[wid] = sum;
    __syncthreads();
    if (threadIdx.x == 0)
        partials[blockIdx.x] = ws[0] + ws[1] + ws[2] + ws[3];
}

__global__ void __launch_bounds__(256)
reduce_partials_kernel(const float* __restrict__ partials, float* __restrict__ out) {
    float s = 0.f;
    for (int i = threadIdx.x; i < NBLOCKS; i += 256)
        s += partials[i];
    #pragma unroll
    for (int off = 32; off > 0; off >>= 1)
        s += __shfl_down(s, off, 64);
    __shared__ float ws[4];
    int lane = threadIdx.x & 63;
    int wid  = threadIdx.x >> 6;
    if (lane == 0) ws[wid] = s;
    __syncthreads();
    if (threadIdx.x == 0)
        out[0] = (ws[0] + ws[1] + ws[2] + ws[3]) * INV_N;
}

extern "C" void kernel_launch(void* const* d_in, const int* in_sizes, int n_in,
                              void* d_out, int out_size, void* d_ws, size_t ws_size,
                              hipStream_t stream) {
    const float* x  = (const float*)d_in[0];
    const float* gt = (const float*)d_in[1];
    float* out      = (float*)d_out;
    float* partials = (float*)d_ws;       // NBLOCKS floats = 6 KB

    scharr_loss_kernel<<<NBLOCKS, 256, 0, stream>>>(x, gt, partials);
    reduce_partials_kernel<<<1, 256, 0, stream>>>(partials, out);
}

// Round 3
// 29.592 us; speedup vs baseline: 5.8390x; 1.0610x over previous
//
#include <hip/hip_runtime.h>

#define Wd 512
#define Hd 512
#define NIMG 48                  // 16 batch * 3 channels
#define ROWS 8                   // output rows per wave-strip
#define STRIPS (NIMG * (Hd / ROWS))   // 48 * 64 = 3072 strips
#define NBLOCKS (STRIPS / 4)          // 4 waves per block -> 768 blocks
constexpr float INV_N = 1.0f / (float)((long long)NIMG * Hd * Wd);

// Scharr on a 3x10 window; pixel j (0..7) uses cols j..j+2 of rows r0,r1,r2.
__device__ __forceinline__ float scharr_pix(const float r0[10], const float r1[10],
                                            const float r2[10], int j) {
    float tl = r0[j], tm = r0[j + 1], tr = r0[j + 2];
    float ml = r1[j],                  mr = r1[j + 2];
    float bl = r2[j], bm = r2[j + 1], br = r2[j + 2];
    float gx = 3.f * (tr - tl) + 10.f * (mr - ml) + 3.f * (br - bl);
    float gy = 3.f * (bl - tl) + 10.f * (bm - tm) + 3.f * (br - tr);
    return fabsf(gx) + fabsf(gy);
}

// Load cols [c0-1 .. c0+8] of row h. Lane covers 8 cols via two float4s;
// horizontal halo comes from neighbor lanes via shfl (wave spans the full row,
// so lane edges == image edges -> zero). h is wave-uniform -> no divergence.
__device__ __forceinline__ void load_row(const float* __restrict__ img, int h,
                                         int c0, int lane, float r[10]) {
    if ((unsigned)h < (unsigned)Hd) {
        const float* p = img + (size_t)h * Wd + c0;
        float4 b0 = *reinterpret_cast<const float4*>(p);
        float4 b1 = *reinterpret_cast<const float4*>(p + 4);
        r[1] = b0.x; r[2] = b0.y; r[3] = b0.z; r[4] = b0.w;
        r[5] = b1.x; r[6] = b1.y; r[7] = b1.z; r[8] = b1.w;
        float lv = __shfl_up(b1.w, 1, 64);    // lane-1's col c0-1
        float rv = __shfl_down(b0.x, 1, 64);  // lane+1's col c0+8
        r[0] = (lane > 0)  ? lv : 0.f;        // image left edge -> 0
        r[9] = (lane < 63) ? rv : 0.f;        // image right edge -> 0
    } else {
        #pragma unroll
        for (int k = 0; k < 10; ++k) r[k] = 0.f;
    }
}

__global__ void __launch_bounds__(256)
scharr_loss_kernel(const float* __restrict__ x, const float* __restrict__ gt,
                   float* __restrict__ partials) {
    int wid   = threadIdx.x >> 6;
    int lane  = threadIdx.x & 63;
    int strip = blockIdx.x * 4 + wid;     // consecutive strips share halo rows
    int img   = strip >> 6;               // 64 strips per image
    int h0    = (strip & 63) * ROWS;
    int c0    = lane * 8;

    const float* __restrict__ xb = x  + (size_t)img * Hd * Wd;
    const float* __restrict__ gb = gt + (size_t)img * Hd * Wd;

    // Rolling 3-row windows, fully unrolled -> all indices compile-time.
    float rx[3][10], rg[3][10];
    load_row(xb, h0 - 1, c0, lane, rx[0]);
    load_row(xb, h0,     c0, lane, rx[1]);
    load_row(gb, h0 - 1, c0, lane, rg[0]);
    load_row(gb, h0,     c0, lane, rg[1]);

    float sum = 0.f;
    #pragma unroll
    for (int i = 0; i < ROWS; ++i) {
        const int c0i = i % 3, c1i = (i + 1) % 3, c2i = (i + 2) % 3;
        load_row(xb, h0 + i + 1, c0, lane, rx[c2i]);
        load_row(gb, h0 + i + 1, c0, lane, rg[c2i]);
        #pragma unroll
        for (int j = 0; j < 8; ++j) {
            float a = scharr_pix(rx[c0i], rx[c1i], rx[c2i], j);
            float b = scharr_pix(rg[c0i], rg[c1i], rg[c2i], j);
            sum += fabsf(a - b);
        }
    }

    // wave(64) reduce, then cross-wave via LDS, one plain store per block
    #pragma unroll
    for (int off = 32; off > 0; off >>= 1)
        sum += __shfl_down(sum, off, 64);

    __shared__ float ws[4];
    if (lane == 0) ws[wid] = sum;
    __syncthreads();
    if (threadIdx.x == 0)
        partials[blockIdx.x] = ws[0] + ws[1] + ws[2] + ws[3];
}

__global__ void __launch_bounds__(256)
reduce_partials_kernel(const float* __restrict__ partials, float* __restrict__ out) {
    float s = 0.f;
    #pragma unroll
    for (int k = 0; k < NBLOCKS / 256; ++k)
        s += partials[k * 256 + threadIdx.x];
    #pragma unroll
    for (int off = 32; off > 0; off >>= 1)
        s += __shfl_down(s, off, 64);
    __shared__ float ws[4];
    int lane = threadIdx.x & 63;
    int wid  = threadIdx.x >> 6;
    if (lane == 0) ws[wid] = s;
    __syncthreads();
    if (threadIdx.x == 0)
        out[0] = (ws[0] + ws[1] + ws[2] + ws[3]) * INV_N;
}

extern "C" void kernel_launch(void* const* d_in, const int* in_sizes, int n_in,
                              void* d_out, int out_size, void* d_ws, size_t ws_size,
                              hipStream_t stream) {
    const float* x  = (const float*)d_in[0];
    const float* gt = (const float*)d_in[1];
    float* out      = (float*)d_out;
    float* partials = (float*)d_ws;       // NBLOCKS floats = 3 KB

    scharr_loss_kernel<<<NBLOCKS, 256, 0, stream>>>(x, gt, partials);
    reduce_partials_kernel<<<1, 256, 0, stream>>>(partials, out);
}